// Round 3
// baseline (256.437 us; speedup 1.0000x reference)
//
#include <hip/hip_runtime.h>
#include <hip/hip_bf16.h>
#include <math.h>
#include <stdint.h>

// Problem constants
#define T_ROWS 16384
#define D_DIM  4096
#define E_EXP  64
#define TOPK   8

constexpr float H_SCALE = 16.0f;       // exact pow2: keeps f16 lo parts in range
constexpr float W_SCALE = 64.0f;
constexpr float INV_SCALE = 1.0f / (16.0f * 64.0f);

typedef _Float16 f16x8 __attribute__((ext_vector_type(8)));
typedef _Float16 f16x4 __attribute__((ext_vector_type(4)));
typedef float    f32x4 __attribute__((ext_vector_type(4)));

// ---------------------------------------------------------------------------
// K0: W (f32 [64][4096]) -> Whi/Wlo (f16, scaled by 64). 1 MB, L2-resident.
// Identical arithmetic to the round-2 cvt (bit-exact outputs).
// ---------------------------------------------------------------------------
__global__ __launch_bounds__(256) void wprep_kernel(
    const float* __restrict__ W, _Float16* __restrict__ Whi,
    _Float16* __restrict__ Wlo)
{
    const int i = blockIdx.x * 256 + threadIdx.x;    // 65536 threads x 4 elems
    const float4 w = ((const float4*)W)[i];
    const float x[4] = {w.x * W_SCALE, w.y * W_SCALE, w.z * W_SCALE, w.w * W_SCALE};
    f16x4 hi, lo;
    #pragma unroll
    for (int j = 0; j < 4; ++j) {
        _Float16 hh = (_Float16)x[j];
        hi[j] = hh;
        lo[j] = (_Float16)(x[j] - (float)hh);
    }
    *(f16x4*)(Whi + (size_t)i * 4) = hi;
    *(f16x4*)(Wlo + (size_t)i * 4) = lo;
}

// ---------------------------------------------------------------------------
// K1: barrier-free streaming router. 1 wave/block, 16 rows/wave, full E=64.
// A: global->reg (4-slot prefetch). B: Whi/Wlo from L1/L2 (2-slot ping-pong).
// ---------------------------------------------------------------------------
__device__ __forceinline__ void cvt8(const float4& a, const float4& b,
                                     f16x8& hi, f16x8& lo) {
    const float x[8] = {a.x, a.y, a.z, a.w, b.x, b.y, b.z, b.w};
    #pragma unroll
    for (int j = 0; j < 8; ++j) {
        const float s = x[j] * H_SCALE;
        const _Float16 hh = (_Float16)s;
        hi[j] = hh;
        lo[j] = (_Float16)(s - (float)hh);
    }
}

// per-chunk body: convert A slot, 12 MFMAs (hh,hl,lh per e-tile, same order as
// the verified round-2 kernel), then refill A slot (c+4) and B slot (c+2).
#define BODY(c, AS, BS)                                                          \
  {                                                                              \
    f16x8 ah, al;                                                                \
    cvt8(aA##AS, aB##AS, ah, al);                                                \
    _Pragma("unroll")                                                            \
    for (int et = 0; et < 4; ++et) {                                             \
      acc[et] = __builtin_amdgcn_mfma_f32_16x16x32_f16(ah, bh##BS[et], acc[et], 0, 0, 0); \
      acc[et] = __builtin_amdgcn_mfma_f32_16x16x32_f16(ah, bl##BS[et], acc[et], 0, 0, 0); \
      acc[et] = __builtin_amdgcn_mfma_f32_16x16x32_f16(al, bh##BS[et], acc[et], 0, 0, 0); \
    }                                                                            \
    {                                                                            \
      const int cn = ((c) + 4) & 127;                                            \
      aA##AS = *(const float4*)(ap + (size_t)cn * 32);                           \
      aB##AS = *(const float4*)(ap + (size_t)cn * 32 + 4);                       \
    }                                                                            \
    {                                                                            \
      const int cn = ((c) + 2) & 127;                                            \
      _Pragma("unroll")                                                          \
      for (int et = 0; et < 4; ++et) {                                           \
        bh##BS[et] = *(const f16x8*)(bhp[et] + (size_t)cn * 32);                 \
        bl##BS[et] = *(const f16x8*)(blp[et] + (size_t)cn * 32);                 \
      }                                                                          \
    }                                                                            \
  }

__global__ __launch_bounds__(64) void router_main_kernel(
    const float* __restrict__ h, const _Float16* __restrict__ Whi,
    const _Float16* __restrict__ Wlo, const float* __restrict__ u,
    float* __restrict__ out)
{
    const int lane = threadIdx.x;          // 0..63
    const int rsub = lane & 15;            // row-in-tile / expert-in-tile
    const int kg   = lane >> 4;            // k-group 0..3
    const int row0 = blockIdx.x * 16;

    // A: lane reads h[row0+rsub][chunk*32 + kg*8 .. +8]
    const float* ap = h + (size_t)(row0 + rsub) * D_DIM + kg * 8;
    // B: lane reads W*[et*16+rsub][chunk*32 + kg*8 .. +8]
    const _Float16* bhp[4];
    const _Float16* blp[4];
    #pragma unroll
    for (int et = 0; et < 4; ++et) {
        const size_t off = (size_t)(et * 16 + rsub) * D_DIM + kg * 8;
        bhp[et] = Whi + off;
        blp[et] = Wlo + off;
    }

    f32x4 acc[4] = {};
    float4 aA0, aB0, aA1, aB1, aA2, aB2, aA3, aB3;
    f16x8 bh0[4], bl0[4], bh1[4], bl1[4];

    // prologue: A chunks 0..3, B chunks 0..1 in flight
    aA0 = *(const float4*)(ap);           aB0 = *(const float4*)(ap + 4);
    aA1 = *(const float4*)(ap + 32);      aB1 = *(const float4*)(ap + 36);
    aA2 = *(const float4*)(ap + 64);      aB2 = *(const float4*)(ap + 68);
    aA3 = *(const float4*)(ap + 96);      aB3 = *(const float4*)(ap + 100);
    #pragma unroll
    for (int et = 0; et < 4; ++et) {
        bh0[et] = *(const f16x8*)(bhp[et]);
        bl0[et] = *(const f16x8*)(blp[et]);
        bh1[et] = *(const f16x8*)(bhp[et] + 32);
        bl1[et] = *(const f16x8*)(blp[et] + 32);
    }

    for (int mc = 0; mc < 128; mc += 4) {
        BODY(mc + 0, 0, 0)
        BODY(mc + 1, 1, 1)
        BODY(mc + 2, 2, 0)
        BODY(mc + 3, 3, 1)
    }

    // ---- epilogue: transpose 16 rows to lane=expert via tiny per-wave LDS ----
    __shared__ float lg[16 * (E_EXP + 1)];
    #pragma unroll
    for (int et = 0; et < 4; ++et)
        #pragma unroll
        for (int r = 0; r < 4; ++r)
            lg[(kg * 4 + r) * (E_EXP + 1) + et * 16 + rsub] = acc[et][r] * INV_SCALE;
    __syncthreads();

    const size_t te = (size_t)T_ROWS * E_EXP;
    for (int rr = 0; rr < 16; ++rr) {
        const int gr = row0 + rr;
        const size_t idx = (size_t)gr * E_EXP + lane;
        const float val = lg[rr * (E_EXP + 1) + lane];

        out[2 * te + idx] = val;                      // logits_clean

        float m = val;
        #pragma unroll
        for (int off = 32; off; off >>= 1) m = fmaxf(m, __shfl_xor(m, off));
        const float p = expf(val - m);
        float ssum = p;
        #pragma unroll
        for (int off = 32; off; off >>= 1) ssum += __shfl_xor(ssum, off);
        out[1 * te + idx] = p / ssum;                 // probs

        const float uv = u[idx];
        const float g = -logf(-logf(uv));
        const float sel = val + g;
        out[3 * te + idx] = sel;                      // logits_sel

        // top-8, ties -> lowest lane (= lowest expert, matches lax.top_k)
        float v = sel;
        bool chosen = false;
        #pragma unroll
        for (int itk = 0; itk < TOPK; ++itk) {
            float mv = v;
            #pragma unroll
            for (int off = 32; off; off >>= 1) mv = fmaxf(mv, __shfl_xor(mv, off));
            const unsigned long long b = __ballot(v == mv);
            const int sl = __ffsll((long long)b) - 1;
            if (lane == sl) { chosen = true; v = -INFINITY; }
        }
        out[idx] = chosen ? 1.0f : 0.0f;              // mask
    }
}

// ---------------------------------------------------------------------------
extern "C" void kernel_launch(void* const* d_in, const int* in_sizes, int n_in,
                              void* d_out, int out_size, void* d_ws, size_t ws_size,
                              hipStream_t stream) {
    const float* h = (const float*)d_in[0];
    const float* W = (const float*)d_in[1];
    const float* u = (const float*)d_in[2];
    float* out = (float*)d_out;

    _Float16* Whi = (_Float16*)d_ws;                       // 512 KB
    _Float16* Wlo = Whi + (size_t)E_EXP * D_DIM;           // 512 KB

    hipLaunchKernelGGL(wprep_kernel, dim3(E_EXP * D_DIM / 4 / 256), dim3(256),
                       0, stream, W, Whi, Wlo);
    hipLaunchKernelGGL(router_main_kernel, dim3(T_ROWS / 16), dim3(64),
                       0, stream, h, Whi, Wlo, u, out);
}

// Round 5
// 127.876 us; speedup vs baseline: 2.0054x; 2.0054x over previous
//
#include <hip/hip_runtime.h>
#include <hip/hip_bf16.h>
#include <math.h>
#include <stdint.h>

// Problem constants
#define T_ROWS 16384
#define D_DIM  4096
#define E_EXP  64
#define TOPK   8

constexpr float W_SCALE   = 64.0f;      // folded into Whi/Wlo by wprep
constexpr float INV_SCALE = 1.0f / 64.0f;

constexpr int ROWS_PER_BLK = 32;        // 2 m-tiles of 16, all 64 experts
constexpr int KSPLIT = 4;               // waves per block, one k-quarter each
constexpr int KQ     = D_DIM / KSPLIT;  // 1024
constexpr int CHUNKS = KQ / 32;         // 32 chunks of k=32

typedef _Float16 f16x8 __attribute__((ext_vector_type(8)));
typedef _Float16 f16x4 __attribute__((ext_vector_type(4)));
typedef __fp16   h16x2 __attribute__((ext_vector_type(2)));
typedef float    f32x4 __attribute__((ext_vector_type(4)));

// ---------------------------------------------------------------------------
// K0: W (f32 [64][4096]) -> Whi/Wlo (f16, scaled by 64). 1 MB, L2-resident.
// ---------------------------------------------------------------------------
__global__ __launch_bounds__(256) void wprep_kernel(
    const float* __restrict__ W, _Float16* __restrict__ Whi,
    _Float16* __restrict__ Wlo)
{
    const int i = blockIdx.x * 256 + threadIdx.x;
    const float4 w = ((const float4*)W)[i];
    const float x[4] = {w.x * W_SCALE, w.y * W_SCALE, w.z * W_SCALE, w.w * W_SCALE};
    f16x4 hi, lo;
    #pragma unroll
    for (int j = 0; j < 4; ++j) {
        _Float16 hh = (_Float16)x[j];
        hi[j] = hh;
        lo[j] = (_Float16)(x[j] - (float)hh);
    }
    *(f16x4*)(Whi + (size_t)i * 4) = hi;
    *(f16x4*)(Wlo + (size_t)i * 4) = lo;
}

// ---------------------------------------------------------------------------
// exact split of f32 into (f16-exact hi) + lo, packed conversion
// ---------------------------------------------------------------------------
__device__ __forceinline__ void cvt8(const float4 x0, const float4 x1,
                                     f16x8& hi, f16x8& lo) {
    const float xs[8] = {x0.x, x0.y, x0.z, x0.w, x1.x, x1.y, x1.z, x1.w};
    float hs[8], ls[8];
    #pragma unroll
    for (int j = 0; j < 8; ++j) {
        hs[j] = __uint_as_float(__float_as_uint(xs[j]) & 0xFFFFE000u);
        ls[j] = xs[j] - hs[j];
    }
    #pragma unroll
    for (int j = 0; j < 4; ++j) {
        const h16x2 ph = __builtin_amdgcn_cvt_pkrtz(hs[2 * j], hs[2 * j + 1]);
        const h16x2 pl = __builtin_amdgcn_cvt_pkrtz(ls[2 * j], ls[2 * j + 1]);
        hi[2 * j] = (_Float16)ph[0]; hi[2 * j + 1] = (_Float16)ph[1];
        lo[2 * j] = (_Float16)pl[0]; lo[2 * j + 1] = (_Float16)pl[1];
    }
}

// per-chunk body. AS: A slot (0/1). BU: B slot used. BP: B slot prefetched.
#define BODY(c, AS, BU, BP, PFA, PFB)                                          \
  {                                                                            \
    f16x8 ah0, al0, ah1, al1;                                                  \
    cvt8(a##AS[0][0], a##AS[0][1], ah0, al0);                                  \
    cvt8(a##AS[1][0], a##AS[1][1], ah1, al1);                                  \
    if (PFA) {                                                                 \
      const int cn = (c) + 2;                                                  \
      a##AS[0][0] = *(const float4*)(ap0 + cn * 32);                           \
      a##AS[0][1] = *(const float4*)(ap0 + cn * 32 + 4);                       \
      a##AS[1][0] = *(const float4*)(ap1 + cn * 32);                           \
      a##AS[1][1] = *(const float4*)(ap1 + cn * 32 + 4);                       \
    }                                                                          \
    if (PFB) {                                                                 \
      const int cn = (c) + 1;                                                  \
      _Pragma("unroll")                                                        \
      for (int et = 0; et < 4; ++et) {                                         \
        b##BP##h[et] = *(const f16x8*)(bhp + (size_t)et * 16 * D_DIM + cn * 32);\
        b##BP##l[et] = *(const f16x8*)(blp + (size_t)et * 16 * D_DIM + cn * 32);\
      }                                                                        \
    }                                                                          \
    _Pragma("unroll")                                                          \
    for (int et = 0; et < 4; ++et) {                                           \
      acc0[et] = __builtin_amdgcn_mfma_f32_16x16x32_f16(ah0, b##BU##h[et], acc0[et], 0, 0, 0); \
      acc0[et] = __builtin_amdgcn_mfma_f32_16x16x32_f16(ah0, b##BU##l[et], acc0[et], 0, 0, 0); \
      acc0[et] = __builtin_amdgcn_mfma_f32_16x16x32_f16(al0, b##BU##h[et], acc0[et], 0, 0, 0); \
      acc1[et] = __builtin_amdgcn_mfma_f32_16x16x32_f16(ah1, b##BU##h[et], acc1[et], 0, 0, 0); \
      acc1[et] = __builtin_amdgcn_mfma_f32_16x16x32_f16(ah1, b##BU##l[et], acc1[et], 0, 0, 0); \
      acc1[et] = __builtin_amdgcn_mfma_f32_16x16x32_f16(al1, b##BU##h[et], acc1[et], 0, 0, 0); \
    }                                                                          \
  }

// ---------------------------------------------------------------------------
// K1: fused router. Block = 32 rows x 4 waves (k-split 4), no main-loop LDS.
// ---------------------------------------------------------------------------
__global__ __launch_bounds__(256, 2) void router_main_kernel(
    const float* __restrict__ h, const _Float16* __restrict__ Whi,
    const _Float16* __restrict__ Wlo, const float* __restrict__ u,
    float* __restrict__ out)
{
    const int tid  = threadIdx.x;
    const int wv   = tid >> 6;           // k-quarter 0..3
    const int lane = tid & 63;
    const int l15  = lane & 15;
    const int kg   = lane >> 4;          // 0..3
    const int row0 = blockIdx.x * ROWS_PER_BLK;
    const int qb   = wv * KQ;

    // A: lane reads h[row0 + mt*16 + l15][qb + c*32 + kg*8 .. +8]
    const float* ap0 = h + (size_t)(row0 + l15) * D_DIM + qb + kg * 8;
    const float* ap1 = ap0 + (size_t)16 * D_DIM;
    // B: lane reads W*[et*16 + l15][qb + c*32 + kg*8 .. +8]
    const _Float16* bhp = Whi + (size_t)l15 * D_DIM + qb + kg * 8;
    const _Float16* blp = Wlo + (size_t)l15 * D_DIM + qb + kg * 8;

    f32x4 acc0[4] = {};
    f32x4 acc1[4] = {};
    float4 a0[2][2], a1[2][2];
    f16x8 b0h[4], b0l[4], b1h[4], b1l[4];

    // prologue: A chunks 0,1; B chunk 0
    a0[0][0] = *(const float4*)(ap0);      a0[0][1] = *(const float4*)(ap0 + 4);
    a0[1][0] = *(const float4*)(ap1);      a0[1][1] = *(const float4*)(ap1 + 4);
    a1[0][0] = *(const float4*)(ap0 + 32); a1[0][1] = *(const float4*)(ap0 + 36);
    a1[1][0] = *(const float4*)(ap1 + 32); a1[1][1] = *(const float4*)(ap1 + 36);
    #pragma unroll
    for (int et = 0; et < 4; ++et) {
        b0h[et] = *(const f16x8*)(bhp + (size_t)et * 16 * D_DIM);
        b0l[et] = *(const f16x8*)(blp + (size_t)et * 16 * D_DIM);
    }

    for (int cc = 0; cc < CHUNKS - 2; cc += 2) {
        BODY(cc,     0, 0, 1, true, true)
        BODY(cc + 1, 1, 1, 0, true, true)
    }
    BODY(CHUNKS - 2, 0, 0, 1, false, true)   // c=30, prefetch B31
    BODY(CHUNKS - 1, 1, 1, 0, false, false)  // c=31

    // ---- k-split reduce via LDS, then fused epilogue ----
    __shared__ float part[KSPLIT][ROWS_PER_BLK][E_EXP + 2];
    #pragma unroll
    for (int et = 0; et < 4; ++et)
        #pragma unroll
        for (int r = 0; r < 4; ++r) {
            part[wv][ 0 + kg * 4 + r][et * 16 + l15] = acc0[et][r];
            part[wv][16 + kg * 4 + r][et * 16 + l15] = acc1[et][r];
        }
    __syncthreads();

    const size_t te = (size_t)T_ROWS * E_EXP;
    for (int rr = 0; rr < 8; ++rr) {
        const int rl = wv * 8 + rr;
        const int gr = row0 + rl;
        const size_t idx = (size_t)gr * E_EXP + lane;
        const float val = (part[0][rl][lane] + part[1][rl][lane]
                         + part[2][rl][lane] + part[3][rl][lane]) * INV_SCALE;

        out[2 * te + idx] = val;                      // logits_clean

        float m = val;
        #pragma unroll
        for (int off = 32; off; off >>= 1) m = fmaxf(m, __shfl_xor(m, off));
        const float p = expf(val - m);
        float ssum = p;
        #pragma unroll
        for (int off = 32; off; off >>= 1) ssum += __shfl_xor(ssum, off);
        out[1 * te + idx] = p / ssum;                 // probs

        const float uv = u[idx];
        const float g = -logf(-logf(uv));
        const float sel = val + g;
        out[3 * te + idx] = sel;                      // logits_sel

        // top-8, ties -> lowest lane (= lowest expert, matches lax.top_k)
        float v = sel;
        bool chosen = false;
        #pragma unroll
        for (int itk = 0; itk < TOPK; ++itk) {
            float mv = v;
            #pragma unroll
            for (int off = 32; off; off >>= 1) mv = fmaxf(mv, __shfl_xor(mv, off));
            const unsigned long long b = __ballot(v == mv);
            const int sl = __ffsll((long long)b) - 1;
            if (lane == sl) { chosen = true; v = -INFINITY; }
        }
        out[idx] = chosen ? 1.0f : 0.0f;              // mask
    }
}

// ---------------------------------------------------------------------------
extern "C" void kernel_launch(void* const* d_in, const int* in_sizes, int n_in,
                              void* d_out, int out_size, void* d_ws, size_t ws_size,
                              hipStream_t stream) {
    const float* h = (const float*)d_in[0];
    const float* W = (const float*)d_in[1];
    const float* u = (const float*)d_in[2];
    float* out = (float*)d_out;

    _Float16* Whi = (_Float16*)d_ws;                       // 512 KB
    _Float16* Wlo = Whi + (size_t)E_EXP * D_DIM;           // 512 KB

    hipLaunchKernelGGL(wprep_kernel, dim3(E_EXP * D_DIM / 4 / 256), dim3(256),
                       0, stream, W, Whi, Wlo);
    hipLaunchKernelGGL(router_main_kernel, dim3(T_ROWS / ROWS_PER_BLK), dim3(256),
                       0, stream, h, Whi, Wlo, u, out);
}

// Round 6
// 100.802 us; speedup vs baseline: 2.5440x; 1.2686x over previous
//
#include <hip/hip_runtime.h>
#include <hip/hip_bf16.h>
#include <math.h>
#include <stdint.h>

// Problem constants
#define T_ROWS 16384
#define D_DIM  4096
#define E_EXP  64
#define TOPK   8

constexpr float W_SCALE   = 64.0f;     // folded into Whi/Wlo by wprep
constexpr float INV_SCALE = 1.0f / 64.0f;

constexpr int BM   = 32;               // rows per block
constexpr int BK   = 64;               // k per step
constexpr int NIT  = D_DIM / BK;       // 64
// LDS plan (triple-buffered):
constexpr int ABUF = 8192;             // 32 rows x 64 f32 (16 chunks of 16B/row)
constexpr int BBUF = 16384;            // [hi 8KB | lo 8KB], 64 e x 64 f16 each
constexpr int B_OFF = 3 * ABUF;        // 24576
constexpr int LDS_TOT = B_OFF + 3 * BBUF;  // 73728

typedef _Float16 f16x8 __attribute__((ext_vector_type(8)));
typedef __fp16   h16x2 __attribute__((ext_vector_type(2)));
typedef float    f32x4 __attribute__((ext_vector_type(4)));

__device__ __forceinline__ void gll16(const void* g, void* l) {
    __builtin_amdgcn_global_load_lds(
        (const __attribute__((address_space(1))) void*)g,
        (__attribute__((address_space(3))) void*)l, 16, 0, 0);
}
#define WAITV(n) asm volatile("s_waitcnt vmcnt(" #n ")" ::: "memory")

// ---------------------------------------------------------------------------
// K0: W (f32 [64][4096]) -> swizzled hi/lo f16 tiles.
// Layout: tile t (k-step) = 8KB contiguous: [e][chunk c'][8 f16], where the
// 16B chunk holding k-octet s of expert e sits at c' = s ^ (e&7).
// ---------------------------------------------------------------------------
__global__ __launch_bounds__(256) void wprep_kernel(
    const float* __restrict__ W, _Float16* __restrict__ Whi,
    _Float16* __restrict__ Wlo)
{
    const int i  = blockIdx.x * 256 + threadIdx.x;   // 64*512 threads, 8 k each
    const int e  = i >> 9;
    const int k8 = i & 511;
    const int k  = k8 << 3;
    const int t  = k >> 6;
    const int s  = (k >> 3) & 7;
    const float4 w0 = *(const float4*)&W[(size_t)e * D_DIM + k];
    const float4 w1 = *(const float4*)&W[(size_t)e * D_DIM + k + 4];
    const float xs[8] = {w0.x, w0.y, w0.z, w0.w, w1.x, w1.y, w1.z, w1.w};
    f16x8 hi, lo;
    #pragma unroll
    for (int j = 0; j < 8; ++j) {
        const float x = xs[j] * W_SCALE;
        const _Float16 hh = (_Float16)x;
        hi[j] = hh;
        lo[j] = (_Float16)(x - (float)hh);
    }
    const size_t o = (size_t)t * 4096 + e * 64 + ((s ^ (e & 7)) << 3);
    *(f16x8*)(Whi + o) = hi;
    *(f16x8*)(Wlo + o) = lo;
}

// exact split of f32 into (f16-exact hi via mantissa mask) + lo, packed cvt
__device__ __forceinline__ void cvt8(const float4 x0, const float4 x1,
                                     f16x8& hi, f16x8& lo) {
    const float xs[8] = {x0.x, x0.y, x0.z, x0.w, x1.x, x1.y, x1.z, x1.w};
    float hs[8], ls[8];
    #pragma unroll
    for (int j = 0; j < 8; ++j) {
        hs[j] = __uint_as_float(__float_as_uint(xs[j]) & 0xFFFFE000u);
        ls[j] = xs[j] - hs[j];
    }
    #pragma unroll
    for (int j = 0; j < 4; ++j) {
        const h16x2 ph = __builtin_amdgcn_cvt_pkrtz(hs[2 * j], hs[2 * j + 1]);
        const h16x2 pl = __builtin_amdgcn_cvt_pkrtz(ls[2 * j], ls[2 * j + 1]);
        hi[2 * j] = (_Float16)ph[0]; hi[2 * j + 1] = (_Float16)ph[1];
        lo[2 * j] = (_Float16)pl[0]; lo[2 * j + 1] = (_Float16)pl[1];
    }
}

// ---------------------------------------------------------------------------
// K1: fused router, m97/T3-style pipeline. 512 blocks x 256 thr (4 waves).
// Wave (wm,we) owns rows wm*16..+16 x experts we*32..+32.
// ---------------------------------------------------------------------------
__global__ __launch_bounds__(256, 2) void router_main_kernel(
    const float* __restrict__ h, const _Float16* __restrict__ Whi,
    const _Float16* __restrict__ Wlo, const float* __restrict__ u,
    float* __restrict__ out)
{
    __shared__ union {
        char raw[LDS_TOT];
        float logits[BM][E_EXP + 4];
    } sm;
    char* smb = sm.raw;

    const int tid  = threadIdx.x;
    const int wv   = tid >> 6;
    const int lane = tid & 63;
    const int l15  = lane & 15;
    const int kg   = lane >> 4;          // 0..3
    const int wm   = wv >> 1;            // m-half
    const int we   = wv & 1;             // e-half
    const int row0 = blockIdx.x * BM;

    // ---- staging descriptors ----
    // A: wave stages instrs j = wv*2+p (rows 4j..4j+3); lane: row 4j+kg, chunk l15.
    // Pre-swizzled global source: chunk fetched = l15 ^ (row&7); LDS stays linear.
    const char* gA[2]; int lA[2];
    #pragma unroll
    for (int p = 0; p < 2; ++p) {
        const int j   = wv * 2 + p;
        const int row = j * 4 + kg;
        gA[p] = (const char*)h + (size_t)(row0 + row) * (D_DIM * 4)
                + ((l15 ^ (row & 7)) << 4);
        lA[p] = j * 1024;
    }
    // B: wave stages instrs j = wv*4+q; j<8 -> hi tile part j, else lo part j-8.
    // Source tiles are pre-swizzled by wprep -> purely linear copy.
    const char* gB[4]; int lB[4];
    #pragma unroll
    for (int q = 0; q < 4; ++q) {
        const int j = wv * 4 + q;
        const _Float16* src = (j < 8) ? Whi : Wlo;
        gB[q] = (const char*)src + (size_t)(j & 7) * 1024 + lane * 16;
        lB[q] = B_OFF + j * 1024;
    }

    // ---- ds_read byte offsets (within one buffer set) ----
    int aro[2][2];                       // [kc][piece]
    {
        const int row = wm * 16 + l15, s7 = l15 & 7;
        #pragma unroll
        for (int kc = 0; kc < 2; ++kc)
            #pragma unroll
            for (int q2 = 0; q2 < 2; ++q2)
                aro[kc][q2] = row * 256 + (((kc * 8 + kg * 2 + q2) ^ s7) << 4);
    }
    int bro[2][2][2];                    // [sel hi/lo][es][kc]
    {
        const int s7 = l15 & 7;
        #pragma unroll
        for (int sel = 0; sel < 2; ++sel)
            #pragma unroll
            for (int es = 0; es < 2; ++es)
                #pragma unroll
                for (int kc = 0; kc < 2; ++kc) {
                    const int e = we * 32 + es * 16 + l15;
                    bro[sel][es][kc] = B_OFF + sel * 8192 + e * 128
                                     + (((kc * 4 + kg) ^ s7) << 4);
                }
    }

    f32x4 acc[2] = {};                   // [es]

    // buffer byte-offset triples (values rotate; no runtime array indexing)
    int aCur = 0,     aNxt = ABUF,  aStg = 2 * ABUF;
    int bCur = 0,     bNxt = BBUF,  bStg = 2 * BBUF;

    #define STAGE(t, aAdd, bAdd)                                   \
        { _Pragma("unroll")                                        \
          for (int p = 0; p < 2; ++p)                              \
              gll16(gA[p] + (size_t)(t) * 256, smb + (aAdd) + lA[p]); \
          _Pragma("unroll")                                        \
          for (int q = 0; q < 4; ++q)                              \
              gll16(gB[q] + (size_t)(t) * 8192, smb + (bAdd) + lB[q]); }

    // prologue: stage t=0 and t=1 (12 loads in flight)
    STAGE(0, aCur, bCur)
    STAGE(1, aNxt, bNxt)
    WAITV(6);                            // t=0's 6 loads landed
    __builtin_amdgcn_s_barrier();

    #define COMPUTE(aAdd, bAdd)                                               \
        { float4 av[2][2];                                                    \
          _Pragma("unroll")                                                   \
          for (int kc = 0; kc < 2; ++kc)                                      \
              _Pragma("unroll")                                               \
              for (int q2 = 0; q2 < 2; ++q2)                                  \
                  av[kc][q2] = *(const float4*)(smb + (aAdd) + aro[kc][q2]);  \
          f16x8 bhf[2][2], blf[2][2];                                         \
          _Pragma("unroll")                                                   \
          for (int es = 0; es < 2; ++es)                                      \
              _Pragma("unroll")                                               \
              for (int kc = 0; kc < 2; ++kc) {                                \
                  bhf[es][kc] = *(const f16x8*)(smb + (bAdd) + bro[0][es][kc]);\
                  blf[es][kc] = *(const f16x8*)(smb + (bAdd) + bro[1][es][kc]);\
              }                                                               \
          f16x8 ah[2], al[2];                                                 \
          cvt8(av[0][0], av[0][1], ah[0], al[0]);                             \
          cvt8(av[1][0], av[1][1], ah[1], al[1]);                             \
          _Pragma("unroll")                                                   \
          for (int es = 0; es < 2; ++es)                                      \
              _Pragma("unroll")                                               \
              for (int kc = 0; kc < 2; ++kc) {                                \
                  acc[es] = __builtin_amdgcn_mfma_f32_16x16x32_f16(ah[kc], bhf[es][kc], acc[es], 0, 0, 0); \
                  acc[es] = __builtin_amdgcn_mfma_f32_16x16x32_f16(ah[kc], blf[es][kc], acc[es], 0, 0, 0); \
                  acc[es] = __builtin_amdgcn_mfma_f32_16x16x32_f16(al[kc], bhf[es][kc], acc[es], 0, 0, 0); \
              } }

    // main loop: stage(i+2) -> compute(i) -> vmcnt(6) -> barrier
    for (int i = 0; i < NIT - 2; ++i) {
        STAGE(i + 2, aStg, bStg)
        COMPUTE(aCur, bCur)
        WAITV(6);                        // buf i+1 ready; i+2's 6 stay in flight
        __builtin_amdgcn_s_barrier();
        int t;
        t = aCur; aCur = aNxt; aNxt = aStg; aStg = t;
        t = bCur; bCur = bNxt; bNxt = bStg; bStg = t;
    }
    // tail: i = NIT-2, NIT-1 (no staging)
    COMPUTE(aCur, bCur)
    WAITV(0);
    __builtin_amdgcn_s_barrier();
    COMPUTE(aNxt, bNxt)
    __builtin_amdgcn_s_barrier();        // all LDS reads done -> safe to alias

    // ---- fused epilogue ----
    #pragma unroll
    for (int es = 0; es < 2; ++es)
        #pragma unroll
        for (int r = 0; r < 4; ++r)
            sm.logits[wm * 16 + kg * 4 + r][we * 32 + es * 16 + l15]
                = acc[es][r] * INV_SCALE;
    __syncthreads();

    const size_t te = (size_t)T_ROWS * E_EXP;
    #pragma unroll
    for (int rr = 0; rr < 8; ++rr) {
        const int rl = wv * 8 + rr;
        const int gr = row0 + rl;
        const size_t idx = (size_t)gr * E_EXP + lane;
        const float val = sm.logits[rl][lane];

        out[2 * te + idx] = val;                      // logits_clean

        float m = val;
        #pragma unroll
        for (int off = 32; off; off >>= 1) m = fmaxf(m, __shfl_xor(m, off));
        const float p = expf(val - m);
        float ssum = p;
        #pragma unroll
        for (int off = 32; off; off >>= 1) ssum += __shfl_xor(ssum, off);
        out[1 * te + idx] = p / ssum;                 // probs

        const float uv = u[idx];
        const float g = -logf(-logf(uv));
        const float sel = val + g;
        out[3 * te + idx] = sel;                      // logits_sel

        // top-8, ties -> lowest lane (= lowest expert, matches lax.top_k)
        float v = sel;
        bool chosen = false;
        #pragma unroll
        for (int itk = 0; itk < TOPK; ++itk) {
            float mv = v;
            #pragma unroll
            for (int off = 32; off; off >>= 1) mv = fmaxf(mv, __shfl_xor(mv, off));
            const unsigned long long b = __ballot(v == mv);
            const int sl = __ffsll((long long)b) - 1;
            if (lane == sl) { chosen = true; v = -INFINITY; }
        }
        out[idx] = chosen ? 1.0f : 0.0f;              // mask
    }
}

// ---------------------------------------------------------------------------
extern "C" void kernel_launch(void* const* d_in, const int* in_sizes, int n_in,
                              void* d_out, int out_size, void* d_ws, size_t ws_size,
                              hipStream_t stream) {
    const float* h = (const float*)d_in[0];
    const float* W = (const float*)d_in[1];
    const float* u = (const float*)d_in[2];
    float* out = (float*)d_out;

    _Float16* Whi = (_Float16*)d_ws;                       // 512 KB (swizzled tiles)
    _Float16* Wlo = Whi + (size_t)E_EXP * D_DIM;           // 512 KB

    hipLaunchKernelGGL(wprep_kernel, dim3(E_EXP * D_DIM / 8 / 256), dim3(256),
                       0, stream, W, Whi, Wlo);
    hipLaunchKernelGGL(router_main_kernel, dim3(T_ROWS / BM), dim3(256),
                       0, stream, h, Whi, Wlo, u, out);
}